// Round 1
// baseline (1410.935 us; speedup 1.0000x reference)
//
#include <hip/hip_runtime.h>

#define NN 4096
#define CC 256
#define CQ 32   // C8
#define BB 4

// ---------------------------------------------------------------------------
// Kernel 1: fused QKV projection.
// Treat concat(Wq,Wk,Wv) as 320 output rows; each block computes 16 rows for a
// 256-wide n-tile. W rows staged in LDS (broadcast reads), x reads coalesced.
//   qws[b][d][n] = sum_c Wq[d][c]*x[b][c][n] + bq[d]   (rows 0..31)
//   kws[b][d][n] = ... Wk ...                          (rows 32..63)
//   vws[b][c][n] = ... Wv ...                          (rows 64..319)
// ---------------------------------------------------------------------------
__global__ __launch_bounds__(256) void qkv_proj(
    const float* __restrict__ x,
    const float* __restrict__ Wq, const float* __restrict__ bq,
    const float* __restrict__ Wk, const float* __restrict__ bk,
    const float* __restrict__ Wv, const float* __restrict__ bv,
    float* __restrict__ qws, float* __restrict__ kws, float* __restrict__ vws)
{
    __shared__ float Wl[16 * 256];
    __shared__ float bl[16];
    const int t = threadIdx.x;
    const int g = blockIdx.y;            // row group 0..19 (16 rows each)
    const int b = blockIdx.z;
    const int n = blockIdx.x * 256 + t;

    const float* wsrc; const float* bsrc; int rowbase;
    if (g < 2)      { wsrc = Wq; bsrc = bq; rowbase = g * 16; }
    else if (g < 4) { wsrc = Wk; bsrc = bk; rowbase = (g - 2) * 16; }
    else            { wsrc = Wv; bsrc = bv; rowbase = (g - 4) * 16; }

    #pragma unroll
    for (int i = 0; i < 16; ++i) {
        int f = i * 256 + t;
        Wl[f] = wsrc[rowbase * 256 + f];
    }
    if (t < 16) bl[t] = bsrc[rowbase + t];
    __syncthreads();

    float acc[16];
    #pragma unroll
    for (int r = 0; r < 16; ++r) acc[r] = bl[r];

    const float* xp = x + ((size_t)b * CC) * NN + n;
    for (int c = 0; c < CC; ++c) {
        float xv = xp[(size_t)c * NN];
        #pragma unroll
        for (int r = 0; r < 16; ++r) acc[r] += Wl[r * 256 + c] * xv;
    }

    const int gr0 = g * 16;
    #pragma unroll
    for (int r = 0; r < 16; ++r) {
        int gr = gr0 + r;
        float o = acc[r];
        if (gr < 32)      qws[((size_t)b * CQ + gr)        * NN + n] = o;
        else if (gr < 64) kws[((size_t)b * CQ + (gr - 32)) * NN + n] = o;
        else              vws[((size_t)b * CC + (gr - 64)) * NN + n] = o;
    }
}

// ---------------------------------------------------------------------------
// Kernel 2: St[m,n] = sum_d k[d][m]*q[d][n]; attention_map[b][m][n] =
// softmax over n of row m (this IS the reference's softmax(S, axis=-2)
// transposed: rows of attention_map are contiguous softmaxes).
// Block: 32 m-rows x full n. Pass 1: online (max,sum). Pass 2: recompute
// logits, write exp(s-max)/sum. Thread tile 2 rows x 4 cols per 64-n tile.
// ---------------------------------------------------------------------------
__global__ __launch_bounds__(256) void attn_softmax(
    const float* __restrict__ qmat, const float* __restrict__ kmat,
    float* __restrict__ A)
{
    __shared__ float Kl[CQ * 32];   // [d][m-local]
    __shared__ float Ql[CQ * 64];   // [d][n-local]
    const int t  = threadIdx.x;
    const int tx = t & 15;          // n-sub: cols tx*4..tx*4+3
    const int ty = t >> 4;          // m-sub: rows ty*2..ty*2+1
    const int b  = blockIdx.x >> 7;           // 128 m-blocks per batch
    const int m0 = (blockIdx.x & 127) * 32;

    // load K tile once: Kl[d][ml] = kmat[b][d][m0+ml]
    #pragma unroll
    for (int i = 0; i < 4; ++i) {
        int f = i * 256 + t;
        int d = f >> 5, ml = f & 31;
        Kl[f] = kmat[((size_t)b * CQ + d) * NN + m0 + ml];
    }

    float mrow[2], srow[2];
    mrow[0] = mrow[1] = -1e30f;
    srow[0] = srow[1] = 0.0f;

    // ---- pass 1: online max/sum ----
    for (int nt = 0; nt < NN / 64; ++nt) {
        __syncthreads();
        #pragma unroll
        for (int i = 0; i < 8; ++i) {
            int f = i * 256 + t;
            int d = f >> 6, nl = f & 63;
            Ql[f] = qmat[((size_t)b * CQ + d) * NN + nt * 64 + nl];
        }
        __syncthreads();

        float sv[2][4];
        #pragma unroll
        for (int r = 0; r < 2; ++r)
            #pragma unroll
            for (int j = 0; j < 4; ++j) sv[r][j] = 0.0f;

        #pragma unroll
        for (int d = 0; d < CQ; ++d) {
            float2 kv = *(const float2*)&Kl[d * 32 + ty * 2];
            float4 qv = *(const float4*)&Ql[d * 64 + tx * 4];
            sv[0][0] += kv.x * qv.x; sv[0][1] += kv.x * qv.y;
            sv[0][2] += kv.x * qv.z; sv[0][3] += kv.x * qv.w;
            sv[1][0] += kv.y * qv.x; sv[1][1] += kv.y * qv.y;
            sv[1][2] += kv.y * qv.z; sv[1][3] += kv.y * qv.w;
        }
        #pragma unroll
        for (int r = 0; r < 2; ++r) {
            float tm = fmaxf(fmaxf(sv[r][0], sv[r][1]), fmaxf(sv[r][2], sv[r][3]));
            float nm = fmaxf(mrow[r], tm);
            srow[r] = srow[r] * __expf(mrow[r] - nm)
                    + __expf(sv[r][0] - nm) + __expf(sv[r][1] - nm)
                    + __expf(sv[r][2] - nm) + __expf(sv[r][3] - nm);
            mrow[r] = nm;
        }
    }

    // reduce (max,sum) across the 16 tx-lanes sharing each row (same wave)
    #pragma unroll
    for (int off = 1; off < 16; off <<= 1) {
        #pragma unroll
        for (int r = 0; r < 2; ++r) {
            float pm = __shfl_xor(mrow[r], off, 64);
            float ps = __shfl_xor(srow[r], off, 64);
            float nm = fmaxf(mrow[r], pm);
            srow[r] = srow[r] * __expf(mrow[r] - nm) + ps * __expf(pm - nm);
            mrow[r] = nm;
        }
    }
    float inv[2];
    inv[0] = 1.0f / srow[0];
    inv[1] = 1.0f / srow[1];

    // ---- pass 2: recompute logits, write normalized ----
    for (int nt = 0; nt < NN / 64; ++nt) {
        __syncthreads();
        #pragma unroll
        for (int i = 0; i < 8; ++i) {
            int f = i * 256 + t;
            int d = f >> 6, nl = f & 63;
            Ql[f] = qmat[((size_t)b * CQ + d) * NN + nt * 64 + nl];
        }
        __syncthreads();

        float sv[2][4];
        #pragma unroll
        for (int r = 0; r < 2; ++r)
            #pragma unroll
            for (int j = 0; j < 4; ++j) sv[r][j] = 0.0f;

        #pragma unroll
        for (int d = 0; d < CQ; ++d) {
            float2 kv = *(const float2*)&Kl[d * 32 + ty * 2];
            float4 qv = *(const float4*)&Ql[d * 64 + tx * 4];
            sv[0][0] += kv.x * qv.x; sv[0][1] += kv.x * qv.y;
            sv[0][2] += kv.x * qv.z; sv[0][3] += kv.x * qv.w;
            sv[1][0] += kv.y * qv.x; sv[1][1] += kv.y * qv.y;
            sv[1][2] += kv.y * qv.z; sv[1][3] += kv.y * qv.w;
        }
        #pragma unroll
        for (int r = 0; r < 2; ++r) {
            float4 o;
            o.x = __expf(sv[r][0] - mrow[r]) * inv[r];
            o.y = __expf(sv[r][1] - mrow[r]) * inv[r];
            o.z = __expf(sv[r][2] - mrow[r]) * inv[r];
            o.w = __expf(sv[r][3] - mrow[r]) * inv[r];
            int m = m0 + ty * 2 + r;
            *(float4*)&A[((size_t)b * NN + m) * NN + nt * 64 + tx * 4] = o;
        }
    }
}

// ---------------------------------------------------------------------------
// Kernel 3: o[c][m] = sum_n v[c][n]*A[m][n];  out = x + gamma*o.
// Classic 64x64 tile, K-tile 32, both operands row-contiguous along k.
// LDS rows padded to 36 floats (144 B: breaks stride-32 bank aliasing, keeps
// 16 B alignment for float4 reads). Thread tile 4x4.
// ---------------------------------------------------------------------------
__global__ __launch_bounds__(256) void out_matmul(
    const float* __restrict__ vws, const float* __restrict__ A,
    const float* __restrict__ x, const float* __restrict__ gamma,
    float* __restrict__ out)
{
    __shared__ float Vl[64 * 36];
    __shared__ float Al[64 * 36];
    const int t  = threadIdx.x;
    const int tx = t & 15;               // m-sub: m0 + tx*4..+3
    const int ty = t >> 4;               // c-sub: c0 + ty*4..+3
    const int m0 = blockIdx.x * 64;
    const int c0 = blockIdx.y * 64;
    const int b  = blockIdx.z;

    float acc[4][4] = {};
    const float* vbase = vws + ((size_t)b * CC + c0) * NN;
    const float* abase = A   + ((size_t)b * NN + m0) * NN;

    for (int kt = 0; kt < NN / 32; ++kt) {
        __syncthreads();
        #pragma unroll
        for (int i = 0; i < 8; ++i) {
            int f  = i * 256 + t;
            int rl = f >> 5, kk = f & 31;
            Vl[rl * 36 + kk] = vbase[(size_t)rl * NN + kt * 32 + kk];
            Al[rl * 36 + kk] = abase[(size_t)rl * NN + kt * 32 + kk];
        }
        __syncthreads();

        #pragma unroll
        for (int kk = 0; kk < 32; kk += 4) {
            float4 va[4], aa[4];
            #pragma unroll
            for (int i = 0; i < 4; ++i) va[i] = *(const float4*)&Vl[(ty * 4 + i) * 36 + kk];
            #pragma unroll
            for (int j = 0; j < 4; ++j) aa[j] = *(const float4*)&Al[(tx * 4 + j) * 36 + kk];
            #pragma unroll
            for (int i = 0; i < 4; ++i)
                #pragma unroll
                for (int j = 0; j < 4; ++j)
                    acc[i][j] += va[i].x * aa[j].x + va[i].y * aa[j].y
                               + va[i].z * aa[j].z + va[i].w * aa[j].w;
        }
    }

    const float g = gamma[0];
    #pragma unroll
    for (int i = 0; i < 4; ++i) {
        int c = c0 + ty * 4 + i;
        size_t rowoff = ((size_t)b * CC + c) * NN + m0 + tx * 4;
        float4 xv = *(const float4*)&x[rowoff];
        float4 o;
        o.x = xv.x + g * acc[i][0];
        o.y = xv.y + g * acc[i][1];
        o.z = xv.z + g * acc[i][2];
        o.w = xv.w + g * acc[i][3];
        *(float4*)&out[rowoff] = o;
    }
}

// ---------------------------------------------------------------------------
extern "C" void kernel_launch(void* const* d_in, const int* in_sizes, int n_in,
                              void* d_out, int out_size, void* d_ws, size_t ws_size,
                              hipStream_t stream) {
    const float* x     = (const float*)d_in[0];
    const float* Wq    = (const float*)d_in[1];
    const float* bq    = (const float*)d_in[2];
    const float* Wk    = (const float*)d_in[3];
    const float* bk    = (const float*)d_in[4];
    const float* Wv    = (const float*)d_in[5];
    const float* bv    = (const float*)d_in[6];
    const float* gamma = (const float*)d_in[7];

    float* out = (float*)d_out;                       // [B, C, H, W]
    float* A   = out + (size_t)BB * CC * NN;          // [B, N, N] attention_map

    float* qws = (float*)d_ws;                        // [B, 32, N]
    float* kws = qws + (size_t)BB * CQ * NN;          // [B, 32, N]
    float* vws = kws + (size_t)BB * CQ * NN;          // [B, 256, N]

    qkv_proj    <<<dim3(NN / 256, 20, BB), 256, 0, stream>>>(x, Wq, bq, Wk, bk, Wv, bv, qws, kws, vws);
    attn_softmax<<<dim3(BB * (NN / 32)),   256, 0, stream>>>(qws, kws, A);
    out_matmul  <<<dim3(NN / 64, CC / 64, BB), 256, 0, stream>>>(vws, A, x, gamma, out);
}

// Round 2
// 785.743 us; speedup vs baseline: 1.7957x; 1.7957x over previous
//
#include <hip/hip_runtime.h>

#define NN 4096
#define CC 256
#define CQ 32   // C8
#define BB 4

typedef short bf16x8 __attribute__((ext_vector_type(8)));
typedef float f32x4  __attribute__((ext_vector_type(4)));

static __device__ inline unsigned short f2bf(float f) {
    unsigned int u = __float_as_uint(f);
    u += 0x7fff + ((u >> 16) & 1);           // round-to-nearest-even
    return (unsigned short)(u >> 16);
}

// ---------------------------------------------------------------------------
// Kernel 1: fused QKV projection (unchanged from R1).
// ---------------------------------------------------------------------------
__global__ __launch_bounds__(256) void qkv_proj(
    const float* __restrict__ x,
    const float* __restrict__ Wq, const float* __restrict__ bq,
    const float* __restrict__ Wk, const float* __restrict__ bk,
    const float* __restrict__ Wv, const float* __restrict__ bv,
    float* __restrict__ qws, float* __restrict__ kws, float* __restrict__ vws)
{
    __shared__ float Wl[16 * 256];
    __shared__ float bl[16];
    const int t = threadIdx.x;
    const int g = blockIdx.y;            // row group 0..19 (16 rows each)
    const int b = blockIdx.z;
    const int n = blockIdx.x * 256 + t;

    const float* wsrc; const float* bsrc; int rowbase;
    if (g < 2)      { wsrc = Wq; bsrc = bq; rowbase = g * 16; }
    else if (g < 4) { wsrc = Wk; bsrc = bk; rowbase = (g - 2) * 16; }
    else            { wsrc = Wv; bsrc = bv; rowbase = (g - 4) * 16; }

    #pragma unroll
    for (int i = 0; i < 16; ++i) {
        int f = i * 256 + t;
        Wl[f] = wsrc[rowbase * 256 + f];
    }
    if (t < 16) bl[t] = bsrc[rowbase + t];
    __syncthreads();

    float acc[16];
    #pragma unroll
    for (int r = 0; r < 16; ++r) acc[r] = bl[r];

    const float* xp = x + ((size_t)b * CC) * NN + n;
    for (int c = 0; c < CC; ++c) {
        float xv = xp[(size_t)c * NN];
        #pragma unroll
        for (int r = 0; r < 16; ++r) acc[r] += Wl[r * 256 + c] * xv;
    }

    const int gr0 = g * 16;
    #pragma unroll
    for (int r = 0; r < 16; ++r) {
        int gr = gr0 + r;
        float o = acc[r];
        if (gr < 32)      qws[((size_t)b * CQ + gr)        * NN + n] = o;
        else if (gr < 64) kws[((size_t)b * CQ + (gr - 32)) * NN + n] = o;
        else              vws[((size_t)b * CC + (gr - 64)) * NN + n] = o;
    }
}

// ---------------------------------------------------------------------------
// Kernel 2: St + softmax over n, writes attention_map rows (unchanged).
// ---------------------------------------------------------------------------
__global__ __launch_bounds__(256) void attn_softmax(
    const float* __restrict__ qmat, const float* __restrict__ kmat,
    float* __restrict__ A)
{
    __shared__ float Kl[CQ * 32];   // [d][m-local]
    __shared__ float Ql[CQ * 64];   // [d][n-local]
    const int t  = threadIdx.x;
    const int tx = t & 15;          // n-sub: cols tx*4..tx*4+3
    const int ty = t >> 4;          // m-sub: rows ty*2..ty*2+1
    const int b  = blockIdx.x >> 7;           // 128 m-blocks per batch
    const int m0 = (blockIdx.x & 127) * 32;

    #pragma unroll
    for (int i = 0; i < 4; ++i) {
        int f = i * 256 + t;
        int d = f >> 5, ml = f & 31;
        Kl[f] = kmat[((size_t)b * CQ + d) * NN + m0 + ml];
    }

    float mrow[2], srow[2];
    mrow[0] = mrow[1] = -1e30f;
    srow[0] = srow[1] = 0.0f;

    for (int nt = 0; nt < NN / 64; ++nt) {
        __syncthreads();
        #pragma unroll
        for (int i = 0; i < 8; ++i) {
            int f = i * 256 + t;
            int d = f >> 6, nl = f & 63;
            Ql[f] = qmat[((size_t)b * CQ + d) * NN + nt * 64 + nl];
        }
        __syncthreads();

        float sv[2][4];
        #pragma unroll
        for (int r = 0; r < 2; ++r)
            #pragma unroll
            for (int j = 0; j < 4; ++j) sv[r][j] = 0.0f;

        #pragma unroll
        for (int d = 0; d < CQ; ++d) {
            float2 kv = *(const float2*)&Kl[d * 32 + ty * 2];
            float4 qv = *(const float4*)&Ql[d * 64 + tx * 4];
            sv[0][0] += kv.x * qv.x; sv[0][1] += kv.x * qv.y;
            sv[0][2] += kv.x * qv.z; sv[0][3] += kv.x * qv.w;
            sv[1][0] += kv.y * qv.x; sv[1][1] += kv.y * qv.y;
            sv[1][2] += kv.y * qv.z; sv[1][3] += kv.y * qv.w;
        }
        #pragma unroll
        for (int r = 0; r < 2; ++r) {
            float tm = fmaxf(fmaxf(sv[r][0], sv[r][1]), fmaxf(sv[r][2], sv[r][3]));
            float nm = fmaxf(mrow[r], tm);
            srow[r] = srow[r] * __expf(mrow[r] - nm)
                    + __expf(sv[r][0] - nm) + __expf(sv[r][1] - nm)
                    + __expf(sv[r][2] - nm) + __expf(sv[r][3] - nm);
            mrow[r] = nm;
        }
    }

    #pragma unroll
    for (int off = 1; off < 16; off <<= 1) {
        #pragma unroll
        for (int r = 0; r < 2; ++r) {
            float pm = __shfl_xor(mrow[r], off, 64);
            float ps = __shfl_xor(srow[r], off, 64);
            float nm = fmaxf(mrow[r], pm);
            srow[r] = srow[r] * __expf(mrow[r] - nm) + ps * __expf(pm - nm);
            mrow[r] = nm;
        }
    }
    float inv[2];
    inv[0] = 1.0f / srow[0];
    inv[1] = 1.0f / srow[1];

    for (int nt = 0; nt < NN / 64; ++nt) {
        __syncthreads();
        #pragma unroll
        for (int i = 0; i < 8; ++i) {
            int f = i * 256 + t;
            int d = f >> 6, nl = f & 63;
            Ql[f] = qmat[((size_t)b * CQ + d) * NN + nt * 64 + nl];
        }
        __syncthreads();

        float sv[2][4];
        #pragma unroll
        for (int r = 0; r < 2; ++r)
            #pragma unroll
            for (int j = 0; j < 4; ++j) sv[r][j] = 0.0f;

        #pragma unroll
        for (int d = 0; d < CQ; ++d) {
            float2 kv = *(const float2*)&Kl[d * 32 + ty * 2];
            float4 qv = *(const float4*)&Ql[d * 64 + tx * 4];
            sv[0][0] += kv.x * qv.x; sv[0][1] += kv.x * qv.y;
            sv[0][2] += kv.x * qv.z; sv[0][3] += kv.x * qv.w;
            sv[1][0] += kv.y * qv.x; sv[1][1] += kv.y * qv.y;
            sv[1][2] += kv.y * qv.z; sv[1][3] += kv.y * qv.w;
        }
        #pragma unroll
        for (int r = 0; r < 2; ++r) {
            float4 o;
            o.x = __expf(sv[r][0] - mrow[r]) * inv[r];
            o.y = __expf(sv[r][1] - mrow[r]) * inv[r];
            o.z = __expf(sv[r][2] - mrow[r]) * inv[r];
            o.w = __expf(sv[r][3] - mrow[r]) * inv[r];
            int m = m0 + ty * 2 + r;
            *(float4*)&A[((size_t)b * NN + m) * NN + nt * 64 + tx * 4] = o;
        }
    }
}

// ---------------------------------------------------------------------------
// Kernel 3 (NEW): o[c][m] = sum_n v[c][n]*A[m][n] via bf16 MFMA;
// out = x + gamma*o.
// GEMM per batch: M=C=256 (c), N=4096 (m), K=4096 (n). Tile 128(c)x128(m),
// BK=32. 4 waves in 2x2, each 64x64 via 4x4 grid of 16x16x32 mfma.
// fp32 inputs converted to bf16 during LDS staging. LDS row stride 40 bf16
// (80 B) breaks power-of-2 bank aliasing on b128 fragment reads.
// Register prefetch of the next k-tile overlaps global latency.
// ---------------------------------------------------------------------------
__global__ __launch_bounds__(256) void out_matmul(
    const float* __restrict__ vws, const float* __restrict__ A,
    const float* __restrict__ x, const float* __restrict__ gamma,
    float* __restrict__ out)
{
    __shared__ unsigned short Vl[128 * 40];   // [c_local][k], stride 40
    __shared__ unsigned short Al[128 * 40];   // [m_local][k], stride 40

    const int t  = threadIdx.x;
    const int l  = t & 63;                    // lane
    const int w  = t >> 6;                    // wave 0..3
    const int wm = w >> 1;                    // c-half (0/1)
    const int wn = w & 1;                     // m-half (0/1)
    const int m0 = blockIdx.x * 128;
    const int c0 = blockIdx.y * 128;
    const int b  = blockIdx.z;

    const float* vbase = vws + ((size_t)b * CC + c0) * NN;
    const float* abase = A   + ((size_t)b * NN + m0) * NN;

    // staging assignment: thread t loads rows (t>>3)+i*32, float4-col t&7
    const int r0 = t >> 3;                    // 0..31
    const int c4 = t & 7;                     // 0..7 (float4 within 32-k row)

    f32x4 acc[4][4];
    #pragma unroll
    for (int i = 0; i < 4; ++i)
        #pragma unroll
        for (int j = 0; j < 4; ++j)
            acc[i][j] = (f32x4){0.f, 0.f, 0.f, 0.f};

    float4 pv[4], pa[4];
    #pragma unroll
    for (int i = 0; i < 4; ++i) {
        int row = r0 + i * 32;
        pv[i] = *(const float4*)&vbase[(size_t)row * NN + c4 * 4];
        pa[i] = *(const float4*)&abase[(size_t)row * NN + c4 * 4];
    }

    const int lrow = l & 15;                  // fragment row within 16-group
    const int lk   = (l >> 4) * 8;            // fragment k offset

    for (int kt = 0; kt < NN / 32; ++kt) {
        __syncthreads();                      // LDS free (prev compute done)
        #pragma unroll
        for (int i = 0; i < 4; ++i) {
            int row = r0 + i * 32;
            unsigned short* vd = &Vl[row * 40 + c4 * 4];
            vd[0] = f2bf(pv[i].x); vd[1] = f2bf(pv[i].y);
            vd[2] = f2bf(pv[i].z); vd[3] = f2bf(pv[i].w);
            unsigned short* ad = &Al[row * 40 + c4 * 4];
            ad[0] = f2bf(pa[i].x); ad[1] = f2bf(pa[i].y);
            ad[2] = f2bf(pa[i].z); ad[3] = f2bf(pa[i].w);
        }
        __syncthreads();

        if (kt + 1 < NN / 32) {               // prefetch next k-tile
            int k0 = (kt + 1) * 32;
            #pragma unroll
            for (int i = 0; i < 4; ++i) {
                int row = r0 + i * 32;
                pv[i] = *(const float4*)&vbase[(size_t)row * NN + k0 + c4 * 4];
                pa[i] = *(const float4*)&abase[(size_t)row * NN + k0 + c4 * 4];
            }
        }

        bf16x8 afrag[4], bfrag[4];
        #pragma unroll
        for (int g = 0; g < 4; ++g)
            afrag[g] = *(const bf16x8*)&Vl[(wm * 64 + g * 16 + lrow) * 40 + lk];
        #pragma unroll
        for (int h = 0; h < 4; ++h)
            bfrag[h] = *(const bf16x8*)&Al[(wn * 64 + h * 16 + lrow) * 40 + lk];

        #pragma unroll
        for (int g = 0; g < 4; ++g)
            #pragma unroll
            for (int h = 0; h < 4; ++h)
                acc[g][h] = __builtin_amdgcn_mfma_f32_16x16x32_bf16(
                    afrag[g], bfrag[h], acc[g][h], 0, 0, 0);
    }

    // epilogue: D layout col=lane&15 (m), row=(lane>>4)*4+reg (c)
    const float gm = gamma[0];
    const int mcol = l & 15;
    const int crow = (l >> 4) * 4;
    #pragma unroll
    for (int g = 0; g < 4; ++g) {
        #pragma unroll
        for (int r = 0; r < 4; ++r) {
            int c = c0 + wm * 64 + g * 16 + crow + r;
            size_t rowoff = ((size_t)b * CC + c) * NN;
            #pragma unroll
            for (int h = 0; h < 4; ++h) {
                int m = m0 + wn * 64 + h * 16 + mcol;
                out[rowoff + m] = x[rowoff + m] + gm * acc[g][h][r];
            }
        }
    }
}

// ---------------------------------------------------------------------------
extern "C" void kernel_launch(void* const* d_in, const int* in_sizes, int n_in,
                              void* d_out, int out_size, void* d_ws, size_t ws_size,
                              hipStream_t stream) {
    const float* x     = (const float*)d_in[0];
    const float* Wq    = (const float*)d_in[1];
    const float* bq    = (const float*)d_in[2];
    const float* Wk    = (const float*)d_in[3];
    const float* bk    = (const float*)d_in[4];
    const float* Wv    = (const float*)d_in[5];
    const float* bv    = (const float*)d_in[6];
    const float* gamma = (const float*)d_in[7];

    float* out = (float*)d_out;                       // [B, C, H, W]
    float* A   = out + (size_t)BB * CC * NN;          // [B, N, N] attention_map

    float* qws = (float*)d_ws;                        // [B, 32, N]
    float* kws = qws + (size_t)BB * CQ * NN;          // [B, 32, N]
    float* vws = kws + (size_t)BB * CQ * NN;          // [B, 256, N]

    qkv_proj    <<<dim3(NN / 256, 20, BB), 256, 0, stream>>>(x, Wq, bq, Wk, bk, Wv, bv, qws, kws, vws);
    attn_softmax<<<dim3(BB * (NN / 32)),   256, 0, stream>>>(qws, kws, A);
    out_matmul  <<<dim3(NN / 128, CC / 128, BB), 256, 0, stream>>>(vws, A, x, gamma, out);
}

// Round 3
// 629.030 us; speedup vs baseline: 2.2430x; 1.2491x over previous
//
#include <hip/hip_runtime.h>

#define NN 4096
#define CC 256
#define CQ 32   // C8
#define BB 4

typedef _Float16 f16x8 __attribute__((ext_vector_type(8)));
typedef _Float16 f16x4 __attribute__((ext_vector_type(4)));
typedef float    f32x4 __attribute__((ext_vector_type(4)));

// ---------------------------------------------------------------------------
// Kernel 1: fused QKV projection.
// NEW outputs: qT [b][n][32] f16 (k-contiguous, MFMA-operand layout),
//              kT [b][m][32] f16, v [b][c][n] f16.
// ---------------------------------------------------------------------------
__global__ __launch_bounds__(256) void qkv_proj(
    const float* __restrict__ x,
    const float* __restrict__ Wq, const float* __restrict__ bq,
    const float* __restrict__ Wk, const float* __restrict__ bk,
    const float* __restrict__ Wv, const float* __restrict__ bv,
    _Float16* __restrict__ qT, _Float16* __restrict__ kT,
    _Float16* __restrict__ vf)
{
    __shared__ float Wl[16 * 256];
    __shared__ float bl[16];
    const int t = threadIdx.x;
    const int g = blockIdx.y;            // row group 0..19 (16 rows each)
    const int b = blockIdx.z;
    const int n = blockIdx.x * 256 + t;

    const float* wsrc; const float* bsrc; int rowbase;
    if (g < 2)      { wsrc = Wq; bsrc = bq; rowbase = g * 16; }
    else if (g < 4) { wsrc = Wk; bsrc = bk; rowbase = (g - 2) * 16; }
    else            { wsrc = Wv; bsrc = bv; rowbase = (g - 4) * 16; }

    #pragma unroll
    for (int i = 0; i < 16; ++i) {
        int f = i * 256 + t;
        Wl[f] = wsrc[rowbase * 256 + f];
    }
    if (t < 16) bl[t] = bsrc[rowbase + t];
    __syncthreads();

    float acc[16];
    #pragma unroll
    for (int r = 0; r < 16; ++r) acc[r] = bl[r];

    const float* xp = x + ((size_t)b * CC) * NN + n;
    for (int c = 0; c < CC; ++c) {
        float xv = xp[(size_t)c * NN];
        #pragma unroll
        for (int r = 0; r < 16; ++r) acc[r] += Wl[r * 256 + c] * xv;
    }

    if (g < 4) {
        f16x8 h0, h1;
        #pragma unroll
        for (int r = 0; r < 8; ++r) { h0[r] = (_Float16)acc[r]; h1[r] = (_Float16)acc[8 + r]; }
        _Float16* dst = (g < 2) ? qT : kT;
        int half = (g < 2) ? g : (g - 2);
        size_t base = ((size_t)b * NN + n) * CQ + half * 16;
        *(f16x8*)&dst[base]     = h0;
        *(f16x8*)&dst[base + 8] = h1;
    } else {
        const int c0 = (g - 4) * 16;
        #pragma unroll
        for (int r = 0; r < 16; ++r)
            vf[((size_t)b * CC + c0 + r) * NN + n] = (_Float16)acc[r];
    }
}

// ---------------------------------------------------------------------------
// Kernel 2a: softmax stats. Block owns 128 m-rows; loops 32 n-tiles of 128.
// Logits via mfma_f32_16x16x32_f16 (K=32 = full d). Online (max, expsum)
// per row in registers -> shfl reduce -> LDS cross-wave -> stats[b][m].
// ---------------------------------------------------------------------------
__global__ __launch_bounds__(256) void attn_stats(
    const _Float16* __restrict__ qT, const _Float16* __restrict__ kT,
    float2* __restrict__ stats)
{
    __shared__ _Float16 Kl[128 * 40];
    __shared__ _Float16 Ql[128 * 40];
    __shared__ float2 sred[2][128];
    const int t  = threadIdx.x;
    const int l  = t & 63, w = t >> 6;
    const int wm = w >> 1, wn = w & 1;
    const int m0 = blockIdx.x * 128;
    const int b  = blockIdx.y;
    const int lrow = l & 15, lk = (l >> 4) * 8;

    #pragma unroll
    for (int i = 0; i < 2; ++i) {
        int c = t + i * 256, row = c >> 2, c4 = c & 3;
        *(f16x8*)&Kl[row * 40 + c4 * 8] =
            *(const f16x8*)&kT[((size_t)b * NN + m0 + row) * CQ + c4 * 8];
    }

    float mrow[4][4], srow[4][4];
    #pragma unroll
    for (int g = 0; g < 4; ++g)
        #pragma unroll
        for (int r = 0; r < 4; ++r) { mrow[g][r] = -1e30f; srow[g][r] = 0.0f; }

    for (int nt = 0; nt < NN / 128; ++nt) {
        __syncthreads();
        #pragma unroll
        for (int i = 0; i < 2; ++i) {
            int c = t + i * 256, row = c >> 2, c4 = c & 3;
            *(f16x8*)&Ql[row * 40 + c4 * 8] =
                *(const f16x8*)&qT[((size_t)b * NN + nt * 128 + row) * CQ + c4 * 8];
        }
        __syncthreads();

        f16x8 af[4], bf[4];
        #pragma unroll
        for (int g = 0; g < 4; ++g)
            af[g] = *(const f16x8*)&Kl[(wm * 64 + g * 16 + lrow) * 40 + lk];
        #pragma unroll
        for (int h = 0; h < 4; ++h)
            bf[h] = *(const f16x8*)&Ql[(wn * 64 + h * 16 + lrow) * 40 + lk];

        #pragma unroll
        for (int g = 0; g < 4; ++g) {
            f32x4 acc[4];
            #pragma unroll
            for (int h = 0; h < 4; ++h) {
                acc[h] = (f32x4){0.f, 0.f, 0.f, 0.f};
                acc[h] = __builtin_amdgcn_mfma_f32_16x16x32_f16(af[g], bf[h], acc[h], 0, 0, 0);
            }
            #pragma unroll
            for (int r = 0; r < 4; ++r) {
                float t0 = fmaxf(fmaxf(acc[0][r], acc[1][r]), fmaxf(acc[2][r], acc[3][r]));
                float nm = fmaxf(mrow[g][r], t0);
                float sadd = __expf(acc[0][r] - nm) + __expf(acc[1][r] - nm)
                           + __expf(acc[2][r] - nm) + __expf(acc[3][r] - nm);
                srow[g][r] = srow[g][r] * __expf(mrow[g][r] - nm) + sadd;
                mrow[g][r] = nm;
            }
        }
    }

    // reduce across the 16 lanes (lane&15) sharing each row
    #pragma unroll
    for (int off = 1; off < 16; off <<= 1) {
        #pragma unroll
        for (int g = 0; g < 4; ++g)
            #pragma unroll
            for (int r = 0; r < 4; ++r) {
                float pm = __shfl_xor(mrow[g][r], off, 64);
                float ps = __shfl_xor(srow[g][r], off, 64);
                float nm = fmaxf(mrow[g][r], pm);
                srow[g][r] = srow[g][r] * __expf(mrow[g][r] - nm) + ps * __expf(pm - nm);
                mrow[g][r] = nm;
            }
    }

    if ((l & 15) == 0) {
        int L = l >> 4;
        #pragma unroll
        for (int g = 0; g < 4; ++g)
            #pragma unroll
            for (int r = 0; r < 4; ++r)
                sred[wn][wm * 64 + g * 16 + L * 4 + r] = make_float2(mrow[g][r], srow[g][r]);
    }
    __syncthreads();

    if (t < 128) {
        float2 a0 = sred[0][t], a1 = sred[1][t];
        float M = fmaxf(a0.x, a1.x);
        float S = a0.y * __expf(a0.x - M) + a1.y * __expf(a1.x - M);
        stats[(size_t)b * NN + m0 + t] = make_float2(M, 1.0f / S);
    }
}

// ---------------------------------------------------------------------------
// Kernel 2b: recompute logits via MFMA, normalize with stats, write A.
// One 128x128 tile per block. Pure write-bound.
// ---------------------------------------------------------------------------
__global__ __launch_bounds__(256) void attn_write(
    const _Float16* __restrict__ qT, const _Float16* __restrict__ kT,
    const float2* __restrict__ stats, float* __restrict__ A)
{
    __shared__ _Float16 Kl[128 * 40];
    __shared__ _Float16 Ql[128 * 40];
    __shared__ float2 sstat[128];
    const int t  = threadIdx.x;
    const int l  = t & 63, w = t >> 6;
    const int wm = w >> 1, wn = w & 1;
    const int n0 = blockIdx.x * 128;
    const int m0 = blockIdx.y * 128;
    const int b  = blockIdx.z;
    const int lrow = l & 15, lk = (l >> 4) * 8;

    #pragma unroll
    for (int i = 0; i < 2; ++i) {
        int c = t + i * 256, row = c >> 2, c4 = c & 3;
        *(f16x8*)&Kl[row * 40 + c4 * 8] =
            *(const f16x8*)&kT[((size_t)b * NN + m0 + row) * CQ + c4 * 8];
        *(f16x8*)&Ql[row * 40 + c4 * 8] =
            *(const f16x8*)&qT[((size_t)b * NN + n0 + row) * CQ + c4 * 8];
    }
    if (t < 128) sstat[t] = stats[(size_t)b * NN + m0 + t];
    __syncthreads();

    f16x8 af[4], bf[4];
    #pragma unroll
    for (int g = 0; g < 4; ++g)
        af[g] = *(const f16x8*)&Kl[(wm * 64 + g * 16 + lrow) * 40 + lk];
    #pragma unroll
    for (int h = 0; h < 4; ++h)
        bf[h] = *(const f16x8*)&Ql[(wn * 64 + h * 16 + lrow) * 40 + lk];

    f32x4 acc[4][4];
    #pragma unroll
    for (int g = 0; g < 4; ++g)
        #pragma unroll
        for (int h = 0; h < 4; ++h) {
            acc[g][h] = (f32x4){0.f, 0.f, 0.f, 0.f};
            acc[g][h] = __builtin_amdgcn_mfma_f32_16x16x32_f16(af[g], bf[h], acc[g][h], 0, 0, 0);
        }

    const int L = l >> 4;
    #pragma unroll
    for (int g = 0; g < 4; ++g) {
        #pragma unroll
        for (int r = 0; r < 4; ++r) {
            int ml = wm * 64 + g * 16 + L * 4 + r;
            float2 st = sstat[ml];
            size_t rb = ((size_t)b * NN + m0 + ml) * NN + n0 + wn * 64 + (l & 15);
            #pragma unroll
            for (int h = 0; h < 4; ++h)
                A[rb + h * 16] = __expf(acc[g][h][r] - st.x) * st.y;
        }
    }
}

// ---------------------------------------------------------------------------
// Kernel 3: o[c][m] = sum_n v[c][n]*A[m][n] via f16 MFMA; out = x + gamma*o.
// V operand now f16 in global (half the fetch, no conversion).
// ---------------------------------------------------------------------------
__global__ __launch_bounds__(256) void out_matmul(
    const _Float16* __restrict__ vf, const float* __restrict__ A,
    const float* __restrict__ x, const float* __restrict__ gamma,
    float* __restrict__ out)
{
    __shared__ _Float16 Vl[128 * 40];   // [c_local][k], stride 40
    __shared__ _Float16 Al[128 * 40];   // [m_local][k], stride 40

    const int t  = threadIdx.x;
    const int l  = t & 63, w = t >> 6;
    const int wm = w >> 1, wn = w & 1;
    const int m0 = blockIdx.x * 128;
    const int c0 = blockIdx.y * 128;
    const int b  = blockIdx.z;

    const _Float16* vbase = vf + ((size_t)b * CC + c0) * NN;
    const float*    abase = A  + ((size_t)b * NN + m0) * NN;

    const int rv = t >> 2, cv = t & 3;   // V: rows rv, rv+64; 8-f16 chunk cv
    const int ra = t >> 3, ca = t & 7;   // A: rows ra+32i;   float4 chunk ca

    f32x4 acc[4][4];
    #pragma unroll
    for (int i = 0; i < 4; ++i)
        #pragma unroll
        for (int j = 0; j < 4; ++j)
            acc[i][j] = (f32x4){0.f, 0.f, 0.f, 0.f};

    f16x8 pv[2]; float4 pa[4];
    #pragma unroll
    for (int i = 0; i < 2; ++i)
        pv[i] = *(const f16x8*)&vbase[(size_t)(rv + i * 64) * NN + cv * 8];
    #pragma unroll
    for (int i = 0; i < 4; ++i)
        pa[i] = *(const float4*)&abase[(size_t)(ra + i * 32) * NN + ca * 4];

    const int lrow = l & 15, lk = (l >> 4) * 8;

    for (int kt = 0; kt < NN / 32; ++kt) {
        __syncthreads();
        #pragma unroll
        for (int i = 0; i < 2; ++i)
            *(f16x8*)&Vl[(rv + i * 64) * 40 + cv * 8] = pv[i];
        #pragma unroll
        for (int i = 0; i < 4; ++i) {
            f16x4 hc;
            hc[0] = (_Float16)pa[i].x; hc[1] = (_Float16)pa[i].y;
            hc[2] = (_Float16)pa[i].z; hc[3] = (_Float16)pa[i].w;
            *(f16x4*)&Al[(ra + i * 32) * 40 + ca * 4] = hc;
        }
        __syncthreads();

        if (kt + 1 < NN / 32) {
            int k0 = (kt + 1) * 32;
            #pragma unroll
            for (int i = 0; i < 2; ++i)
                pv[i] = *(const f16x8*)&vbase[(size_t)(rv + i * 64) * NN + k0 + cv * 8];
            #pragma unroll
            for (int i = 0; i < 4; ++i)
                pa[i] = *(const float4*)&abase[(size_t)(ra + i * 32) * NN + k0 + ca * 4];
        }

        f16x8 afrag[4], bfrag[4];
        #pragma unroll
        for (int g = 0; g < 4; ++g)
            afrag[g] = *(const f16x8*)&Vl[(wm * 64 + g * 16 + lrow) * 40 + lk];
        #pragma unroll
        for (int h = 0; h < 4; ++h)
            bfrag[h] = *(const f16x8*)&Al[(wn * 64 + h * 16 + lrow) * 40 + lk];

        #pragma unroll
        for (int g = 0; g < 4; ++g)
            #pragma unroll
            for (int h = 0; h < 4; ++h)
                acc[g][h] = __builtin_amdgcn_mfma_f32_16x16x32_f16(
                    afrag[g], bfrag[h], acc[g][h], 0, 0, 0);
    }

    // epilogue: D layout col=lane&15 (m), row=(lane>>4)*4+reg (c)
    const float gm = gamma[0];
    const int mcol = l & 15;
    const int crow = (l >> 4) * 4;
    #pragma unroll
    for (int g = 0; g < 4; ++g) {
        #pragma unroll
        for (int r = 0; r < 4; ++r) {
            int c = c0 + wm * 64 + g * 16 + crow + r;
            size_t rowoff = ((size_t)b * CC + c) * NN;
            #pragma unroll
            for (int h = 0; h < 4; ++h) {
                int m = m0 + wn * 64 + h * 16 + mcol;
                out[rowoff + m] = x[rowoff + m] + gm * acc[g][h][r];
            }
        }
    }
}

// ---------------------------------------------------------------------------
extern "C" void kernel_launch(void* const* d_in, const int* in_sizes, int n_in,
                              void* d_out, int out_size, void* d_ws, size_t ws_size,
                              hipStream_t stream) {
    const float* x     = (const float*)d_in[0];
    const float* Wq    = (const float*)d_in[1];
    const float* bq    = (const float*)d_in[2];
    const float* Wk    = (const float*)d_in[3];
    const float* bk    = (const float*)d_in[4];
    const float* Wv    = (const float*)d_in[5];
    const float* bv    = (const float*)d_in[6];
    const float* gamma = (const float*)d_in[7];

    float* out = (float*)d_out;                       // [B, C, H, W]
    float* A   = out + (size_t)BB * CC * NN;          // [B, N, N] attention_map

    _Float16* qT = (_Float16*)d_ws;                   // [B, N, 32]
    _Float16* kT = qT + (size_t)BB * NN * CQ;         // [B, N, 32]
    _Float16* vf = kT + (size_t)BB * NN * CQ;         // [B, C, N]
    float2* stats = (float2*)(vf + (size_t)BB * CC * NN);  // [B, N]

    qkv_proj  <<<dim3(NN / 256, 20, BB), 256, 0, stream>>>(x, Wq, bq, Wk, bk, Wv, bv, qT, kT, vf);
    attn_stats<<<dim3(NN / 128, BB),     256, 0, stream>>>(qT, kT, stats);
    attn_write<<<dim3(NN / 128, NN / 128, BB), 256, 0, stream>>>(qT, kT, stats, A);
    out_matmul<<<dim3(NN / 128, CC / 128, BB), 256, 0, stream>>>(vf, A, x, gamma, out);
}